// Round 14
// baseline (112.076 us; speedup 1.0000x reference)
//
#include <hip/hip_runtime.h>
#include <math.h>

#define DCH 256      // d_model
#define BSZ 512      // graphs
#define NPG 200      // nodes per graph
#define G4  1024     // 4*D
#define K2  512      // 2*D
#define KSD 4        // k-split for gates GEMM (grid 8x8x4 = 256 blocks)
#define NCHK (BSZ * NPG * 32)   // node uint4 chunks (3,276,800)
#define WCHK (65536 + 16384)    // wcat + wobf chunks

typedef __attribute__((ext_vector_type(8))) short short8v;  // 8 bf16
typedef __attribute__((ext_vector_type(4))) float f32x4;

__device__ __forceinline__ float sigf(float x) { return 1.0f / (1.0f + __expf(-x)); }

// ---- bf16 pack/unpack (RNE) ----
__device__ __forceinline__ unsigned pack2bf(float a, float b) {
    unsigned ua = __float_as_uint(a), ub = __float_as_uint(b);
    ua = (ua + 0x7FFFu + ((ua >> 16) & 1u)) >> 16;
    ub = (ub + 0x7FFFu + ((ub >> 16) & 1u)) & 0xFFFF0000u;
    return ua | ub;           // a -> low16, b -> high16
}
__device__ __forceinline__ float lo_bf(unsigned u) { return __uint_as_float(u << 16); }
__device__ __forceinline__ float hi_bf(unsigned u) { return __uint_as_float(u & 0xFFFF0000u); }

// ---------------------------------------------------------------------------
// convert: pure streaming fp32 -> bf16. nbf is a LINEAR repack of node
// (nbf[i] = pack(node[8i..8i+7])), plus Wcat/WoBf weight chunks appended.
// 2048 blocks x 256 thr, grid-stride: the fill-kernel regime (~7 TB/s).
// ---------------------------------------------------------------------------
__global__ __launch_bounds__(256) void convert_kernel(
    const float* __restrict__ node,
    const float* __restrict__ W_ih, const float* __restrict__ W_hh,
    const float* __restrict__ Wo,
    uint4* __restrict__ nbf, uint4* __restrict__ wcat, uint4* __restrict__ wobf)
{
    const int stride = gridDim.x * blockDim.x;
    for (int i = blockIdx.x * blockDim.x + threadIdx.x; i < NCHK + WCHK; i += stride) {
        if (i < NCHK) {
            const float4 v0 = *(const float4*)(node + (size_t)i * 8);
            const float4 v1 = *(const float4*)(node + (size_t)i * 8 + 4);
            uint4 u;
            u.x = pack2bf(v0.x, v0.y); u.y = pack2bf(v0.z, v0.w);
            u.z = pack2bf(v1.x, v1.y); u.w = pack2bf(v1.z, v1.w);
            nbf[i] = u;
        } else {
            int idx = i - NCHK;
            if (idx < 65536) {                     // Wcat chunk
                const int n = idx >> 6, k = (idx & 63) * 8;
                float v[8];
                *(float4*)(v)     = *(const float4*)(W_ih + (size_t)n * K2 + k);
                *(float4*)(v + 4) = *(const float4*)(W_ih + (size_t)n * K2 + k + 4);
                if (k < DCH) {
                    float h[8];
                    *(float4*)(h)     = *(const float4*)(W_hh + (size_t)n * DCH + k);
                    *(float4*)(h + 4) = *(const float4*)(W_hh + (size_t)n * DCH + k + 4);
                    #pragma unroll
                    for (int q = 0; q < 8; ++q) v[q] += h[q];
                }
                uint4 u;
                u.x = pack2bf(v[0], v[1]); u.y = pack2bf(v[2], v[3]);
                u.z = pack2bf(v[4], v[5]); u.w = pack2bf(v[6], v[7]);
                wcat[idx] = u;
            } else {                               // WoBf chunk
                const int i2 = idx - 65536;
                const int n = i2 >> 6, k = (i2 & 63) * 8;
                float v[8];
                *(float4*)(v)     = *(const float4*)(Wo + (size_t)n * K2 + k);
                *(float4*)(v + 4) = *(const float4*)(Wo + (size_t)n * K2 + k + 4);
                uint4 u;
                u.x = pack2bf(v[0], v[1]); u.y = pack2bf(v[2], v[3]);
                u.z = pack2bf(v[4], v[5]); u.w = pack2bf(v[6], v[7]);
                wobf[i2] = u;
            }
        }
    }
}

// ---------------------------------------------------------------------------
// MFMA gates GEMM partial (round-10 proven):
// gpart[z][m][n] = sum_{k in slice z} qstar_bf[m,k] * Wcat[n,k]
// D: row = gate (A side) = (lane>>4)*4 + reg, col = graph (B side) = lane&15
// ---------------------------------------------------------------------------
__global__ __launch_bounds__(256) void gemm_gates_mfma(
    const unsigned short* __restrict__ hrbf,   // [BSZ][512] bf16 q_star
    const unsigned short* __restrict__ wcat,   // [1024][512] bf16
    float* __restrict__ gpart, int Kper)
{
    const int wid  = threadIdx.x >> 6;
    const int lane = threadIdx.x & 63;
    const int gx = blockIdx.x * 128 + wid * 32;   // gate base (A side)
    const int gm = blockIdx.y * 64;               // graph base (B side)
    const int kbase = blockIdx.z * Kper;
    const int rsel = lane & 15, kgrp = lane >> 4;

    f32x4 a0m0 = {}, a0m1 = {}, a0m2 = {}, a0m3 = {},
          a1m0 = {}, a1m1 = {}, a1m2 = {}, a1m3 = {};

    for (int k0 = 0; k0 < Kper; k0 += 32) {
        const int kk = kbase + k0 + kgrp * 8;
        short8v wa0 = *(const short8v*)(wcat + (size_t)(gx +  0 + rsel) * K2 + kk);
        short8v wa1 = *(const short8v*)(wcat + (size_t)(gx + 16 + rsel) * K2 + kk);
        short8v qb0 = *(const short8v*)(hrbf + (size_t)(gm +  0 + rsel) * K2 + kk);
        short8v qb1 = *(const short8v*)(hrbf + (size_t)(gm + 16 + rsel) * K2 + kk);
        short8v qb2 = *(const short8v*)(hrbf + (size_t)(gm + 32 + rsel) * K2 + kk);
        short8v qb3 = *(const short8v*)(hrbf + (size_t)(gm + 48 + rsel) * K2 + kk);
        a0m0 = __builtin_amdgcn_mfma_f32_16x16x32_bf16(wa0, qb0, a0m0, 0, 0, 0);
        a0m1 = __builtin_amdgcn_mfma_f32_16x16x32_bf16(wa0, qb1, a0m1, 0, 0, 0);
        a0m2 = __builtin_amdgcn_mfma_f32_16x16x32_bf16(wa0, qb2, a0m2, 0, 0, 0);
        a0m3 = __builtin_amdgcn_mfma_f32_16x16x32_bf16(wa0, qb3, a0m3, 0, 0, 0);
        a1m0 = __builtin_amdgcn_mfma_f32_16x16x32_bf16(wa1, qb0, a1m0, 0, 0, 0);
        a1m1 = __builtin_amdgcn_mfma_f32_16x16x32_bf16(wa1, qb1, a1m1, 0, 0, 0);
        a1m2 = __builtin_amdgcn_mfma_f32_16x16x32_bf16(wa1, qb2, a1m2, 0, 0, 0);
        a1m3 = __builtin_amdgcn_mfma_f32_16x16x32_bf16(wa1, qb3, a1m3, 0, 0, 0);
    }

    float* Cp = gpart + (size_t)blockIdx.z * BSZ * G4;
    const int gr = kgrp * 4;
    #define STORE_ACC(ni, mi, accv) \
        *(f32x4*)(Cp + (size_t)(gm + (mi)*16 + rsel) * G4 + gx + (ni)*16 + gr) = (accv);
    STORE_ACC(0, 0, a0m0) STORE_ACC(0, 1, a0m1) STORE_ACC(0, 2, a0m2) STORE_ACC(0, 3, a0m3)
    STORE_ACC(1, 0, a1m0) STORE_ACC(1, 1, a1m1) STORE_ACC(1, 2, a1m2) STORE_ACC(1, 3, a1m3)
    #undef STORE_ACC
}

// ---------------------------------------------------------------------------
// All 4 passes: fused LSTM + online-softmax attention over bf16 node cache
// (+ out-proj if LAST). FIRST: gates = biases only, c_old = 0.
// 256 thr = 16 clusters x 16 lanes; depth-2 prefetch; no stores in node loop.
// smem (4640 floats): qs[512] | red_r[16][256] @512 | red_m @4608 | red_s @4624
// ---------------------------------------------------------------------------
template<int FIRST, int LAST>
__global__ __launch_bounds__(256) void lstm_attn_kernel(
    const float* __restrict__ gpart,
    const float* __restrict__ b_ih, const float* __restrict__ b_hh,
    const uint4* __restrict__ nbf, const int* __restrict__ node_num,
    float* __restrict__ cbuf, unsigned* __restrict__ hrbf,
    const uint4* __restrict__ wobf, const float* __restrict__ bo,
    float* __restrict__ outp)
{
    __shared__ __align__(16) float smem[4640];
    float* qs = smem;
    float (*red_r)[DCH] = (float (*)[DCH])(smem + 512);
    float* red_m = smem + 4608;
    float* red_s = smem + 4624;

    const int b = blockIdx.x;
    const int t = threadIdx.x;

    // ---- LSTM cell (torch gate order i,f,g,o) ----
    float gv[4];
    #pragma unroll
    for (int q = 0; q < 4; ++q) {
        const int idx = q * DCH + t;
        float v = b_ih[idx] + b_hh[idx];
        if (!FIRST) {
            #pragma unroll
            for (int z = 0; z < KSD; ++z)
                v += gpart[(size_t)z * BSZ * G4 + (size_t)b * G4 + idx];
        }
        gv[q] = v;
    }
    const float c_old = FIRST ? 0.0f : cbuf[b * DCH + t];
    const float cn = sigf(gv[1]) * c_old + sigf(gv[0]) * tanhf(gv[2]);
    const float hn = sigf(gv[3]) * tanhf(cn);
    if (!LAST) cbuf[b * DCH + t] = cn;
    qs[t] = hn;
    __syncthreads();

    // ---- attention: bf16 cache, 16 clusters, depth-2 prefetch ----
    const int w = t >> 6, l = t & 63;
    const int p = l & 15;
    const int g = w * 4 + (l >> 4);
    const int cnt = node_num[b];
    const uint4* nbf_b = nbf + (size_t)b * NPG * 32;

    float4 qv[4];
    #pragma unroll
    for (int j = 0; j < 2; ++j) {
        qv[j*2+0] = *(const float4*)(qs + j * 128 + p * 8);
        qv[j*2+1] = *(const float4*)(qs + j * 128 + p * 8 + 4);
    }

    auto ld = [&](int n, float4* x) {
        if (n < cnt) {
            #pragma unroll
            for (int j = 0; j < 2; ++j) {
                const uint4 u = nbf_b[(size_t)n * 32 + j * 16 + p];
                x[j*2+0] = make_float4(lo_bf(u.x), hi_bf(u.x), lo_bf(u.y), hi_bf(u.y));
                x[j*2+1] = make_float4(lo_bf(u.z), hi_bf(u.z), lo_bf(u.w), hi_bf(u.w));
            }
        } else {
            x[0] = x[1] = x[2] = x[3] = make_float4(0.f, 0.f, 0.f, 0.f);
        }
    };

    float m = -INFINITY, ssum = 0.0f;
    float4 racc[4] = {};
    const int nit = (cnt + 31) >> 5;

    float4 x0[4], x1[4], u0[4], u1[4];
    ld(2 * g, x0);      ld(2 * g + 1, x1);
    ld(32 + 2 * g, u0); ld(32 + 2 * g + 1, u1);

    for (int it = 0; it < nit; ++it) {
        const int n0 = it * 32 + 2 * g;
        float4 y0[4], y1[4];
        ld(n0 + 64, y0); ld(n0 + 65, y1);

        float e0 = 0.f, e1 = 0.f;
        #pragma unroll
        for (int j = 0; j < 4; ++j) {
            e0 += x0[j].x * qv[j].x + x0[j].y * qv[j].y + x0[j].z * qv[j].z + x0[j].w * qv[j].w;
            e1 += x1[j].x * qv[j].x + x1[j].y * qv[j].y + x1[j].z * qv[j].z + x1[j].w * qv[j].w;
        }
        #pragma unroll
        for (int off = 1; off < 16; off <<= 1) {
            e0 += __shfl_xor(e0, off);
            e1 += __shfl_xor(e1, off);
        }
        if (n0     >= cnt) e0 = -INFINITY;
        if (n0 + 1 >= cnt) e1 = -INFINITY;
        const float mn = fmaxf(m, fmaxf(e0, e1));
        if (mn > -INFINITY) {
            const float sc = __expf(m - mn);
            const float w0 = __expf(e0 - mn);
            const float w1 = __expf(e1 - mn);
            ssum = ssum * sc + w0 + w1;
            #pragma unroll
            for (int j = 0; j < 4; ++j) {
                racc[j].x = racc[j].x * sc + w0 * x0[j].x + w1 * x1[j].x;
                racc[j].y = racc[j].y * sc + w0 * x0[j].y + w1 * x1[j].y;
                racc[j].z = racc[j].z * sc + w0 * x0[j].z + w1 * x1[j].z;
                racc[j].w = racc[j].w * sc + w0 * x0[j].w + w1 * x1[j].w;
            }
            m = mn;
        }
        #pragma unroll
        for (int j = 0; j < 4; ++j) {
            x0[j] = u0[j]; x1[j] = u1[j];
            u0[j] = y0[j]; u1[j] = y1[j];
        }
    }

    #pragma unroll
    for (int j = 0; j < 2; ++j) {
        *(float4*)(&red_r[g][j * 128 + p * 8])     = racc[j*2+0];
        *(float4*)(&red_r[g][j * 128 + p * 8 + 4]) = racc[j*2+1];
    }
    if (p == 0) { red_m[g] = m; red_s[g] = ssum; }
    __syncthreads();

    float M = -INFINITY;
    #pragma unroll
    for (int g2 = 0; g2 < 16; ++g2) M = fmaxf(M, red_m[g2]);
    float stot = 0.0f, rtot = 0.0f;
    #pragma unroll
    for (int g2 = 0; g2 < 16; ++g2) {
        const float sc = __expf(red_m[g2] - M);
        stot += sc * red_s[g2];
        rtot += sc * red_r[g2][t];
    }
    rtot = rtot / (stot + 1e-6f);

    qs[256 + t] = rtot;            // q_star = [h | r]
    __syncthreads();

    if (!LAST) {
        hrbf[b * 256 + t] = pack2bf(qs[2 * t], qs[2 * t + 1]);
        return;
    }

    // ---- fused output projection (Wo bf16) ----
    float4 qv2[8];
    #pragma unroll
    for (int j = 0; j < 4; ++j) {
        qv2[j*2+0] = *(const float4*)(qs + j * 128 + p * 8);
        qv2[j*2+1] = *(const float4*)(qs + j * 128 + p * 8 + 4);
    }
    float* out_sm = smem + 512;    // reuse red_r (post-barrier)

    #pragma unroll 2
    for (int v = 0; v < 8; ++v) {
        const int o0 = (2 * v) * 16 + g;
        const int o1 = o0 + 16;
        float e0 = 0.f, e1 = 0.f;
        #pragma unroll
        for (int j = 0; j < 4; ++j) {
            const uint4 ua = wobf[(size_t)o0 * 64 + j * 16 + p];
            const uint4 ub = wobf[(size_t)o1 * 64 + j * 16 + p];
            e0 += lo_bf(ua.x) * qv2[j*2].x + hi_bf(ua.x) * qv2[j*2].y
                + lo_bf(ua.y) * qv2[j*2].z + hi_bf(ua.y) * qv2[j*2].w
                + lo_bf(ua.z) * qv2[j*2+1].x + hi_bf(ua.z) * qv2[j*2+1].y
                + lo_bf(ua.w) * qv2[j*2+1].z + hi_bf(ua.w) * qv2[j*2+1].w;
            e1 += lo_bf(ub.x) * qv2[j*2].x + hi_bf(ub.x) * qv2[j*2].y
                + lo_bf(ub.y) * qv2[j*2].z + hi_bf(ub.y) * qv2[j*2].w
                + lo_bf(ub.z) * qv2[j*2+1].x + hi_bf(ub.z) * qv2[j*2+1].y
                + lo_bf(ub.w) * qv2[j*2+1].z + hi_bf(ub.w) * qv2[j*2+1].w;
        }
        #pragma unroll
        for (int off = 1; off < 16; off <<= 1) {
            e0 += __shfl_xor(e0, off);
            e1 += __shfl_xor(e1, off);
        }
        if (p == 0) {
            out_sm[o0] = e0 + bo[o0];
            out_sm[o1] = e1 + bo[o1];
        }
    }
    __syncthreads();
    outp[(size_t)b * DCH + t] = out_sm[t];
}

// ---------------------------------------------------------------------------
extern "C" void kernel_launch(void* const* d_in, const int* in_sizes, int n_in,
                              void* d_out, int out_size, void* d_ws, size_t ws_size,
                              hipStream_t stream)
{
    const float* node     = (const float*)d_in[0];
    const int*   node_num = (const int*)  d_in[1];
    const float* W_ih     = (const float*)d_in[2];
    const float* W_hh     = (const float*)d_in[3];
    const float* b_ih     = (const float*)d_in[4];
    const float* b_hh     = (const float*)d_in[5];
    const float* Wo       = (const float*)d_in[6];
    const float* bo       = (const float*)d_in[7];
    float* out = (float*)d_out;

    float* ws      = (float*)d_ws;
    float* cbuf    = ws;                                   // 512*256 f32
    unsigned* hrbf = (unsigned*)(cbuf + BSZ * DCH);        // 512*256 u32
    float* gpart   = (float*)(hrbf + BSZ * 256);           // 4*512*1024 f32 (8 MB)
    uint4* wcat    = (uint4*)(gpart + (size_t)KSD * BSZ * G4);   // 1 MB
    uint4* wobf    = wcat + 1024 * 64;                     // 256 KB
    uint4* nbf     = wobf + 256 * 64;                      // bf16 node cache (52.4 MB)

    // pure streaming conversion: node + weights -> bf16 (fill-kernel regime)
    convert_kernel<<<2048, 256, 0, stream>>>(node, W_ih, W_hh, Wo, nbf, wcat, wobf);

    // step 1: gates = biases only (reads bf16 cache like all passes)
    lstm_attn_kernel<1, 0><<<BSZ, 256, 0, stream>>>(
        nullptr, b_ih, b_hh, nbf, node_num, cbuf, hrbf, wobf, bo, out);

    for (int s = 1; s < 4; ++s) {
        gemm_gates_mfma<<<dim3(8, 8, KSD), 256, 0, stream>>>(
            (const unsigned short*)hrbf, (const unsigned short*)wcat, gpart, K2 / KSD);
        if (s < 3) {
            lstm_attn_kernel<0, 0><<<BSZ, 256, 0, stream>>>(
                gpart, b_ih, b_hh, nbf, node_num, cbuf, hrbf, wobf, bo, out);
        } else {
            lstm_attn_kernel<0, 1><<<BSZ, 256, 0, stream>>>(
                gpart, b_ih, b_hh, nbf, node_num, cbuf, hrbf, wobf, bo, out);
        }
    }
}

// Round 15
// 100.498 us; speedup vs baseline: 1.1152x; 1.1152x over previous
//
#include <hip/hip_runtime.h>
#include <math.h>

#define DCH 256      // d_model
#define BSZ 512      // graphs
#define NPG 200      // nodes per graph
#define G4  1024     // 4*D
#define K2  512      // 2*D
#define KSD 4        // k-split for gates GEMM (grid 8x8x4 = 256 blocks)

typedef __attribute__((ext_vector_type(8))) short short8v;  // 8 bf16
typedef __attribute__((ext_vector_type(4))) float f32x4;

__device__ __forceinline__ float sigf(float x) { return 1.0f / (1.0f + __expf(-x)); }

// ---- bf16 pack/unpack (RNE) ----
__device__ __forceinline__ unsigned pack2bf(float a, float b) {
    unsigned ua = __float_as_uint(a), ub = __float_as_uint(b);
    ua = (ua + 0x7FFFu + ((ua >> 16) & 1u)) >> 16;
    ub = (ub + 0x7FFFu + ((ub >> 16) & 1u)) & 0xFFFF0000u;
    return ua | ub;           // a -> low16, b -> high16
}
__device__ __forceinline__ float lo_bf(unsigned u) { return __uint_as_float(u << 16); }
__device__ __forceinline__ float hi_bf(unsigned u) { return __uint_as_float(u & 0xFFFF0000u); }

// ---------------------------------------------------------------------------
// MFMA gates GEMM partial, operands SWAPPED (A = Wcat rows -> D rows = gates):
// gpart[z][m][n] = sum_{k in slice z} qstar_bf[m,k] * Wcat[n,k]
// D: row = gate (A side) = (lane>>4)*4 + reg, col = graph (B side) = lane&15
// -> each lane stores 8 float4 contiguous in the gate dim.
// ---------------------------------------------------------------------------
__global__ __launch_bounds__(256) void gemm_gates_mfma(
    const unsigned short* __restrict__ hrbf,   // [BSZ][512] bf16 q_star
    const unsigned short* __restrict__ wcat,   // [1024][512] bf16
    float* __restrict__ gpart, int Kper)
{
    const int wid  = threadIdx.x >> 6;
    const int lane = threadIdx.x & 63;
    const int gx = blockIdx.x * 128 + wid * 32;   // gate base (A side)
    const int gm = blockIdx.y * 64;               // graph base (B side)
    const int kbase = blockIdx.z * Kper;
    const int rsel = lane & 15, kgrp = lane >> 4;

    f32x4 a0m0 = {}, a0m1 = {}, a0m2 = {}, a0m3 = {},
          a1m0 = {}, a1m1 = {}, a1m2 = {}, a1m3 = {};

    for (int k0 = 0; k0 < Kper; k0 += 32) {
        const int kk = kbase + k0 + kgrp * 8;
        short8v wa0 = *(const short8v*)(wcat + (size_t)(gx +  0 + rsel) * K2 + kk);
        short8v wa1 = *(const short8v*)(wcat + (size_t)(gx + 16 + rsel) * K2 + kk);
        short8v qb0 = *(const short8v*)(hrbf + (size_t)(gm +  0 + rsel) * K2 + kk);
        short8v qb1 = *(const short8v*)(hrbf + (size_t)(gm + 16 + rsel) * K2 + kk);
        short8v qb2 = *(const short8v*)(hrbf + (size_t)(gm + 32 + rsel) * K2 + kk);
        short8v qb3 = *(const short8v*)(hrbf + (size_t)(gm + 48 + rsel) * K2 + kk);
        a0m0 = __builtin_amdgcn_mfma_f32_16x16x32_bf16(wa0, qb0, a0m0, 0, 0, 0);
        a0m1 = __builtin_amdgcn_mfma_f32_16x16x32_bf16(wa0, qb1, a0m1, 0, 0, 0);
        a0m2 = __builtin_amdgcn_mfma_f32_16x16x32_bf16(wa0, qb2, a0m2, 0, 0, 0);
        a0m3 = __builtin_amdgcn_mfma_f32_16x16x32_bf16(wa0, qb3, a0m3, 0, 0, 0);
        a1m0 = __builtin_amdgcn_mfma_f32_16x16x32_bf16(wa1, qb0, a1m0, 0, 0, 0);
        a1m1 = __builtin_amdgcn_mfma_f32_16x16x32_bf16(wa1, qb1, a1m1, 0, 0, 0);
        a1m2 = __builtin_amdgcn_mfma_f32_16x16x32_bf16(wa1, qb2, a1m2, 0, 0, 0);
        a1m3 = __builtin_amdgcn_mfma_f32_16x16x32_bf16(wa1, qb3, a1m3, 0, 0, 0);
    }

    float* Cp = gpart + (size_t)blockIdx.z * BSZ * G4;
    const int gr = kgrp * 4;              // gate row sub-offset (4 contiguous)
    #define STORE_ACC(ni, mi, accv) \
        *(f32x4*)(Cp + (size_t)(gm + (mi)*16 + rsel) * G4 + gx + (ni)*16 + gr) = (accv);
    STORE_ACC(0, 0, a0m0) STORE_ACC(0, 1, a0m1) STORE_ACC(0, 2, a0m2) STORE_ACC(0, 3, a0m3)
    STORE_ACC(1, 0, a1m0) STORE_ACC(1, 1, a1m1) STORE_ACC(1, 2, a1m2) STORE_ACC(1, 3, a1m3)
    #undef STORE_ACC
}

// ---------------------------------------------------------------------------
// Fused LSTM cell + online-softmax attention (+ out-proj if LAST; + weight
// conversion if FIRST). One block per graph, 256 threads = 16 clusters x 16.
// Lane p of a cluster owns dims {j*128 + p*8 .. +7}. Depth-2 node prefetch.
// smem (4640 floats): qs[512] | red_r[16][256] @512 | red_m @4608 | red_s @4624
// ---------------------------------------------------------------------------
template<int FIRST, int LAST>
__global__ __launch_bounds__(256) void lstm_attn_kernel(
    const float* __restrict__ gpart,
    const float* __restrict__ b_ih, const float* __restrict__ b_hh,
    const float* __restrict__ node, uint4* __restrict__ nbf,
    const int* __restrict__ node_num,
    float* __restrict__ cbuf, unsigned* __restrict__ hrbf,
    const float* __restrict__ W_ih, const float* __restrict__ W_hh,
    const float* __restrict__ Wo,
    uint4* __restrict__ wcat, uint4* __restrict__ wobf,
    const float* __restrict__ bo, float* __restrict__ outp)
{
    __shared__ __align__(16) float smem[4640];
    float* qs = smem;                                  // [512]: h | r
    float (*red_r)[DCH] = (float (*)[DCH])(smem + 512);
    float* red_m = smem + 4608;
    float* red_s = smem + 4624;

    const int b = blockIdx.x;
    const int t = threadIdx.x;

    // ---- fused weight conversion (FIRST only): 160 chunks per block ----
    if (FIRST) {
        if (t < 160) {
            int idx = blockIdx.x * 160 + t;            // 0..81919
            if (idx < 65536) {                         // Wcat chunk
                const int n = idx >> 6, k = (idx & 63) * 8;
                float v[8];
                *(float4*)(v)     = *(const float4*)(W_ih + (size_t)n * K2 + k);
                *(float4*)(v + 4) = *(const float4*)(W_ih + (size_t)n * K2 + k + 4);
                if (k < DCH) {
                    float h[8];
                    *(float4*)(h)     = *(const float4*)(W_hh + (size_t)n * DCH + k);
                    *(float4*)(h + 4) = *(const float4*)(W_hh + (size_t)n * DCH + k + 4);
                    #pragma unroll
                    for (int i = 0; i < 8; ++i) v[i] += h[i];
                }
                uint4 u;
                u.x = pack2bf(v[0], v[1]); u.y = pack2bf(v[2], v[3]);
                u.z = pack2bf(v[4], v[5]); u.w = pack2bf(v[6], v[7]);
                wcat[idx] = u;
            } else {                                   // WoBf chunk
                const int i2 = idx - 65536;
                const int n = i2 >> 6, k = (i2 & 63) * 8;
                float v[8];
                *(float4*)(v)     = *(const float4*)(Wo + (size_t)n * K2 + k);
                *(float4*)(v + 4) = *(const float4*)(Wo + (size_t)n * K2 + k + 4);
                uint4 u;
                u.x = pack2bf(v[0], v[1]); u.y = pack2bf(v[2], v[3]);
                u.z = pack2bf(v[4], v[5]); u.w = pack2bf(v[6], v[7]);
                wobf[i2] = u;
            }
        }
    }

    // ---- LSTM cell (torch gate order i,f,g,o) ----
    float gv[4];
    #pragma unroll
    for (int q = 0; q < 4; ++q) {
        const int idx = q * DCH + t;
        float v = b_ih[idx] + b_hh[idx];
        if (!FIRST) {
            #pragma unroll
            for (int z = 0; z < KSD; ++z)
                v += gpart[(size_t)z * BSZ * G4 + (size_t)b * G4 + idx];
        }
        gv[q] = v;
    }
    const float c_old = FIRST ? 0.0f : cbuf[b * DCH + t];
    const float cn = sigf(gv[1]) * c_old + sigf(gv[0]) * tanhf(gv[2]);
    const float hn = sigf(gv[3]) * tanhf(cn);
    if (!LAST) cbuf[b * DCH + t] = cn;
    qs[t] = hn;
    __syncthreads();

    // ---- attention ----
    const int w = t >> 6, l = t & 63;
    const int p = l & 15;
    const int g = w * 4 + (l >> 4);
    const int cnt = node_num[b];
    const float* nb = node + (size_t)b * NPG * DCH;
    uint4* nbf_b = nbf + (size_t)b * NPG * 32;   // 32 uint4 per node

    float4 qv[4];
    #pragma unroll
    for (int j = 0; j < 2; ++j) {
        qv[j*2+0] = *(const float4*)(qs + j * 128 + p * 8);
        qv[j*2+1] = *(const float4*)(qs + j * 128 + p * 8 + 4);
    }

    auto ld = [&](int n, float4* x) {
        if (n < cnt) {
            if (FIRST) {
                #pragma unroll
                for (int j = 0; j < 2; ++j) {
                    x[j*2+0] = *(const float4*)(nb + (size_t)n * DCH + j * 128 + p * 8);
                    x[j*2+1] = *(const float4*)(nb + (size_t)n * DCH + j * 128 + p * 8 + 4);
                }
            } else {
                #pragma unroll
                for (int j = 0; j < 2; ++j) {
                    const uint4 u = nbf_b[(size_t)n * 32 + j * 16 + p];
                    x[j*2+0] = make_float4(lo_bf(u.x), hi_bf(u.x), lo_bf(u.y), hi_bf(u.y));
                    x[j*2+1] = make_float4(lo_bf(u.z), hi_bf(u.z), lo_bf(u.w), hi_bf(u.w));
                }
            }
        } else {
            x[0] = x[1] = x[2] = x[3] = make_float4(0.f, 0.f, 0.f, 0.f);
        }
    };
    auto st_bf = [&](int n, const float4* x) {
        if (n < cnt) {
            #pragma unroll
            for (int j = 0; j < 2; ++j) {
                uint4 u;
                u.x = pack2bf(x[j*2+0].x, x[j*2+0].y);
                u.y = pack2bf(x[j*2+0].z, x[j*2+0].w);
                u.z = pack2bf(x[j*2+1].x, x[j*2+1].y);
                u.w = pack2bf(x[j*2+1].z, x[j*2+1].w);
                nbf_b[(size_t)n * 32 + j * 16 + p] = u;
            }
        }
    };

    float m = -INFINITY, s = 0.0f;
    float4 racc[4] = {};
    const int nit = (cnt + 31) >> 5;

    // depth-2 pipeline: x = iter it, u = iter it+1, y = prefetch it+2
    float4 x0[4], x1[4], u0[4], u1[4];
    ld(2 * g, x0);      ld(2 * g + 1, x1);
    ld(32 + 2 * g, u0); ld(32 + 2 * g + 1, u1);

    for (int it = 0; it < nit; ++it) {
        const int n0 = it * 32 + 2 * g;
        float4 y0[4], y1[4];
        const int np = n0 + 64;                       // iter it+2
        ld(np, y0); ld(np + 1, y1);
        if (FIRST) { st_bf(n0, x0); st_bf(n0 + 1, x1); }   // build bf16 cache

        float e0 = 0.f, e1 = 0.f;
        #pragma unroll
        for (int j = 0; j < 4; ++j) {
            e0 += x0[j].x * qv[j].x + x0[j].y * qv[j].y + x0[j].z * qv[j].z + x0[j].w * qv[j].w;
            e1 += x1[j].x * qv[j].x + x1[j].y * qv[j].y + x1[j].z * qv[j].z + x1[j].w * qv[j].w;
        }
        #pragma unroll
        for (int off = 1; off < 16; off <<= 1) {
            e0 += __shfl_xor(e0, off);
            e1 += __shfl_xor(e1, off);
        }
        if (n0     >= cnt) e0 = -INFINITY;
        if (n0 + 1 >= cnt) e1 = -INFINITY;
        const float mn = fmaxf(m, fmaxf(e0, e1));
        if (mn > -INFINITY) {
            const float sc = __expf(m - mn);
            const float w0 = __expf(e0 - mn);
            const float w1 = __expf(e1 - mn);
            s = s * sc + w0 + w1;
            #pragma unroll
            for (int j = 0; j < 4; ++j) {
                racc[j].x = racc[j].x * sc + w0 * x0[j].x + w1 * x1[j].x;
                racc[j].y = racc[j].y * sc + w0 * x0[j].y + w1 * x1[j].y;
                racc[j].z = racc[j].z * sc + w0 * x0[j].z + w1 * x1[j].z;
                racc[j].w = racc[j].w * sc + w0 * x0[j].w + w1 * x1[j].w;
            }
            m = mn;
        }
        #pragma unroll
        for (int j = 0; j < 4; ++j) {
            x0[j] = u0[j]; x1[j] = u1[j];
            u0[j] = y0[j]; u1[j] = y1[j];
        }
    }

    #pragma unroll
    for (int j = 0; j < 2; ++j) {
        *(float4*)(&red_r[g][j * 128 + p * 8])     = racc[j*2+0];
        *(float4*)(&red_r[g][j * 128 + p * 8 + 4]) = racc[j*2+1];
    }
    if (p == 0) { red_m[g] = m; red_s[g] = s; }
    __syncthreads();

    float M = -INFINITY;
    #pragma unroll
    for (int g2 = 0; g2 < 16; ++g2) M = fmaxf(M, red_m[g2]);
    float stot = 0.0f, rtot = 0.0f;
    #pragma unroll
    for (int g2 = 0; g2 < 16; ++g2) {
        const float sc = __expf(red_m[g2] - M);
        stot += sc * red_s[g2];
        rtot += sc * red_r[g2][t];
    }
    rtot = rtot / (stot + 1e-6f);

    // q_star = [h | r] into smem
    qs[256 + t] = rtot;
    __syncthreads();

    if (!LAST) {
        // pack q_star -> bf16 hrbf[b][512]
        hrbf[b * 256 + t] = pack2bf(qs[2 * t], qs[2 * t + 1]);
        return;
    }

    // ---- fused output projection: out[b,o] = Wo[o,:]·[h|r] + bo[o], Wo bf16 ----
    float4 qv2[8];
    #pragma unroll
    for (int j = 0; j < 4; ++j) {
        qv2[j*2+0] = *(const float4*)(qs + j * 128 + p * 8);
        qv2[j*2+1] = *(const float4*)(qs + j * 128 + p * 8 + 4);
    }
    float* out_sm = smem + 512;         // reuse red_r area (post-sync)

    #pragma unroll 2
    for (int v = 0; v < 8; ++v) {
        const int o0 = (2 * v) * 16 + g;
        const int o1 = o0 + 16;
        float e0 = 0.f, e1 = 0.f;
        #pragma unroll
        for (int j = 0; j < 4; ++j) {
            const uint4 ua = wobf[(size_t)o0 * 64 + j * 16 + p];
            const uint4 ub = wobf[(size_t)o1 * 64 + j * 16 + p];
            e0 += lo_bf(ua.x) * qv2[j*2].x + hi_bf(ua.x) * qv2[j*2].y
                + lo_bf(ua.y) * qv2[j*2].z + hi_bf(ua.y) * qv2[j*2].w
                + lo_bf(ua.z) * qv2[j*2+1].x + hi_bf(ua.z) * qv2[j*2+1].y
                + lo_bf(ua.w) * qv2[j*2+1].z + hi_bf(ua.w) * qv2[j*2+1].w;
            e1 += lo_bf(ub.x) * qv2[j*2].x + hi_bf(ub.x) * qv2[j*2].y
                + lo_bf(ub.y) * qv2[j*2].z + hi_bf(ub.y) * qv2[j*2].w
                + lo_bf(ub.z) * qv2[j*2+1].x + hi_bf(ub.z) * qv2[j*2+1].y
                + lo_bf(ub.w) * qv2[j*2+1].z + hi_bf(ub.w) * qv2[j*2+1].w;
        }
        #pragma unroll
        for (int off = 1; off < 16; off <<= 1) {
            e0 += __shfl_xor(e0, off);
            e1 += __shfl_xor(e1, off);
        }
        if (p == 0) {
            out_sm[o0] = e0 + bo[o0];
            out_sm[o1] = e1 + bo[o1];
        }
    }
    __syncthreads();
    outp[(size_t)b * DCH + t] = out_sm[t];
}

// ---------------------------------------------------------------------------
extern "C" void kernel_launch(void* const* d_in, const int* in_sizes, int n_in,
                              void* d_out, int out_size, void* d_ws, size_t ws_size,
                              hipStream_t stream)
{
    const float* node     = (const float*)d_in[0];
    const int*   node_num = (const int*)  d_in[1];
    const float* W_ih     = (const float*)d_in[2];
    const float* W_hh     = (const float*)d_in[3];
    const float* b_ih     = (const float*)d_in[4];
    const float* b_hh     = (const float*)d_in[5];
    const float* Wo       = (const float*)d_in[6];
    const float* bo       = (const float*)d_in[7];
    float* out = (float*)d_out;

    float* ws      = (float*)d_ws;
    float* cbuf    = ws;                                   // 512*256 f32
    unsigned* hrbf = (unsigned*)(cbuf + BSZ * DCH);        // 512*256 u32 (bf16 q_star)
    float* gpart   = (float*)(hrbf + BSZ * 256);           // KSD*512*1024 f32 (8 MB)
    uint4* wcat    = (uint4*)(gpart + (size_t)KSD * BSZ * G4);   // 1 MB
    uint4* wobf    = wcat + 1024 * 64;                     // 256 KB
    uint4* nbf     = wobf + 256 * 64;                      // bf16 node cache (52.4 MB)

    // step 1: gates = biases only; builds bf16 node cache + bf16 weights
    lstm_attn_kernel<1, 0><<<BSZ, 256, 0, stream>>>(
        gpart, b_ih, b_hh, node, nbf, node_num, cbuf, hrbf,
        W_ih, W_hh, Wo, wcat, wobf, bo, out);

    for (int s = 1; s < 4; ++s) {
        gemm_gates_mfma<<<dim3(8, 8, KSD), 256, 0, stream>>>(
            (const unsigned short*)hrbf, (const unsigned short*)wcat, gpart, K2 / KSD);
        if (s < 3) {
            lstm_attn_kernel<0, 0><<<BSZ, 256, 0, stream>>>(
                gpart, b_ih, b_hh, node, nbf, node_num, cbuf, hrbf,
                W_ih, W_hh, Wo, wcat, wobf, bo, out);
        } else {
            lstm_attn_kernel<0, 1><<<BSZ, 256, 0, stream>>>(
                gpart, b_ih, b_hh, node, nbf, node_num, cbuf, hrbf,
                W_ih, W_hh, Wo, wcat, wobf, bo, out);
        }
    }
}